// Round 3
// baseline (291.225 us; speedup 1.0000x reference)
//
#include <hip/hip_runtime.h>
#include <hip/hip_bf16.h>
#include <cstdint>
#include <cstddef>

// GCN 2-layer forward, MI355X (gfx950).
//   CSR build -> rowptr/colv + dinv (dinv fused into scan)
//   x -> (xh,xl) bf16 Dekker-split planes; W1,W2 -> transposed split planes
//   hs = bf16( dinv[m] * (x @ W1) )      pure-bf16 MFMA GEMM, 3-term split,
//                                        global_load_lds staging (m97 structure)
//   h1 planes = split( relu(dinv*rowsum(hs) + b1) )   (agg emits split directly)
//   gs = bf16( dinv[m] * (h1 @ W2) )
//   out = relu( dinv*rowsum(gs) + b2 )   fp32

#define WAVE 64

typedef short bf16x8 __attribute__((ext_vector_type(8)));
typedef float f32x4 __attribute__((ext_vector_type(4)));

__device__ __forceinline__ float b2f(unsigned short u) {
    union { unsigned int i; float f; } c; c.i = ((unsigned int)u) << 16; return c.f;
}
__device__ __forceinline__ unsigned short f2b(float f) {
    union { float f; unsigned int i; } c; c.f = f;
    return (unsigned short)((c.i + 0x7FFFu + ((c.i >> 16) & 1u)) >> 16);
}
// Dekker-style split: f = b2f(hi) + b2f(lo) + eps, hi = truncation (exact residual).
__device__ __forceinline__ void split2(float f, unsigned short& hi, unsigned short& lo) {
    union { float f; unsigned int i; } c; c.f = f;
    hi = (unsigned short)(c.i >> 16);
    union { unsigned int i; float f; } h; h.i = c.i & 0xFFFF0000u;
    lo = f2b(f - h.f);
}

// ---------------- CSR build ----------------
__global__ __launch_bounds__(256) void k_fill_i32(int* __restrict__ p, int v, int n) {
    int i = blockIdx.x * 256 + threadIdx.x;
    if (i < n) p[i] = v;
}

__global__ __launch_bounds__(256) void k_count(const int* __restrict__ dst,
                                               int* __restrict__ cnt, int E) {
    int e = blockIdx.x * 256 + threadIdx.x;
    if (e < E) atomicAdd(&cnt[dst[e]], 1);
}

// scan + dinv fused
__global__ __launch_bounds__(256) void k_scan_block(const int* __restrict__ cnt,
                                                    int* __restrict__ rowptr,
                                                    int* __restrict__ partial,
                                                    float* __restrict__ dinv, int n) {
    __shared__ int s[256];
    int i = blockIdx.x * 256 + threadIdx.x;
    int v = (i < n) ? cnt[i] : 0;
    if (i < n) dinv[i] = rsqrtf((float)(v + 1));
    s[threadIdx.x] = v;
    __syncthreads();
    for (int off = 1; off < 256; off <<= 1) {
        int t = (threadIdx.x >= off) ? s[threadIdx.x - off] : 0;
        __syncthreads();
        s[threadIdx.x] += t;
        __syncthreads();
    }
    if (i < n) rowptr[i] = s[threadIdx.x] - v;
    if (threadIdx.x == 255) partial[blockIdx.x] = s[255];
}

__global__ __launch_bounds__(256) void k_scan_partial(int* __restrict__ partial, int nb) {
    __shared__ int s[256];
    int v = (threadIdx.x < nb) ? partial[threadIdx.x] : 0;
    s[threadIdx.x] = v;
    __syncthreads();
    for (int off = 1; off < 256; off <<= 1) {
        int t = (threadIdx.x >= off) ? s[threadIdx.x - off] : 0;
        __syncthreads();
        s[threadIdx.x] += t;
        __syncthreads();
    }
    if (threadIdx.x < nb) partial[threadIdx.x] = s[threadIdx.x] - v;
}

__global__ __launch_bounds__(256) void k_scan_add(int* __restrict__ rowptr,
                                                  const int* __restrict__ partial,
                                                  int n, int e) {
    int i = blockIdx.x * 256 + threadIdx.x;
    if (i < n) rowptr[i] += partial[blockIdx.x];
    if (i == 0) rowptr[n] = e;
}

__global__ __launch_bounds__(256) void k_fill_col(const int* __restrict__ src,
                                                  const int* __restrict__ dst,
                                                  const int* __restrict__ rowptr,
                                                  int* __restrict__ cur,
                                                  int* __restrict__ colv, int E) {
    int e = blockIdx.x * 256 + threadIdx.x;
    if (e < E) {
        int d = dst[e];
        int p = rowptr[d] + atomicAdd(&cur[d], 1);
        colv[p] = src[e];
    }
}

// ---------------- fp32 -> split bf16 planes (elementwise, float4) ----------
__global__ __launch_bounds__(256) void k_split(const float* __restrict__ in,
                                               unsigned short* __restrict__ hi,
                                               unsigned short* __restrict__ lo, int n4) {
    int i = blockIdx.x * 256 + threadIdx.x;
    const int stride = gridDim.x * 256;
    for (; i < n4; i += stride) {
        float4 v = ((const float4*)in)[i];
        ushort4 h, l;
        split2(v.x, h.x, l.x); split2(v.y, h.y, l.y);
        split2(v.z, h.z, l.z); split2(v.w, h.w, l.w);
        ((ushort4*)hi)[i] = h;
        ((ushort4*)lo)[i] = l;
    }
}

// ---------------- transpose + split: src[R][C] -> dh/dl[C][R] --------------
__global__ __launch_bounds__(256) void k_tsplit(const float* __restrict__ src,
                                                unsigned short* __restrict__ dh,
                                                unsigned short* __restrict__ dl,
                                                int R, int C) {
    __shared__ float tile[64][65];
    int r0 = blockIdx.y * 64, c0 = blockIdx.x * 64;
    for (int i = threadIdx.x; i < 4096; i += 256) {
        int r = i >> 6, c = i & 63;
        tile[r][c] = src[(size_t)(r0 + r) * C + c0 + c];
    }
    __syncthreads();
    for (int i = threadIdx.x; i < 4096; i += 256) {
        int r = i >> 6, c = i & 63;
        float v = tile[c][r];
        unsigned short h, l;
        split2(v, h, l);
        size_t o = (size_t)(c0 + r) * R + r0 + c;
        dh[o] = h;
        dl[o] = l;
    }
}

// ---------------- pure-bf16 split GEMM (m97 structure) ----------------------
// C[m][n] = bf16( scale[m] * sum_k (ah+al)[m][k]*(bh+bl)[n][k] ), 3-term.
// A planes [M][K] bf16 (row-clamped at M), B planes [Nc][K] bf16.
// Tile 128x128, BK=32, 4 waves. LDS: 4 linear planes [128][32] bf16 = 32 KB,
// staged via global_load_lds width=16 (wave-uniform LDS base + lane*16).
__global__ __launch_bounds__(256) void k_gemm_split(const unsigned short* __restrict__ Ah,
                                                    const unsigned short* __restrict__ Al,
                                                    const unsigned short* __restrict__ Bh,
                                                    const unsigned short* __restrict__ Bl,
                                                    const float* __restrict__ scale,
                                                    unsigned short* __restrict__ C,
                                                    int M, int K, int Nc) {
    __shared__ __align__(16) unsigned short lds[4 * 128 * 32];  // planes: Ah Al Bh Bl
    const int tid = threadIdx.x;
    const int m0 = blockIdx.x * 128, n0 = blockIdx.y * 128;
    const int w = tid >> 6, lane = tid & 63;
    const int wr = w >> 1, wc = w & 1;
    const int fr = lane & 15, kg = lane >> 4;

    f32x4 acc[4][4] = {};

    for (int k0 = 0; k0 < K; k0 += 32) {
#pragma unroll
        for (int c = 0; c < 8; ++c) {
            const int r = c * 4 + w;            // 64-chunk run id, wave-uniform
            const int plane = r >> 3;           // wave-uniform
            const int wch = (r & 7) * 64 + lane;
            const int row = wch >> 2;           // 0..127
            const int kc = (wch & 3) * 8;       // bf16 offset 0/8/16/24
            const unsigned short* gp;
            if (plane == 0) {
                int rg = m0 + row; rg = rg < M ? rg : M - 1;
                gp = Ah + (size_t)rg * K + k0 + kc;
            } else if (plane == 1) {
                int rg = m0 + row; rg = rg < M ? rg : M - 1;
                gp = Al + (size_t)rg * K + k0 + kc;
            } else if (plane == 2) {
                gp = Bh + (size_t)(n0 + row) * K + k0 + kc;
            } else {
                gp = Bl + (size_t)(n0 + row) * K + k0 + kc;
            }
            __builtin_amdgcn_global_load_lds(
                (const __attribute__((address_space(1))) void*)gp,
                (__attribute__((address_space(3))) void*)(lds + (size_t)r * 512),
                16, 0, 0);
        }
        __syncthreads();
        bf16x8 ah[4], al[4], bh[4], bl[4];
#pragma unroll
        for (int i = 0; i < 4; ++i) {
            const int ar = wr * 64 + i * 16 + fr;
            ah[i] = *(const bf16x8*)&lds[0 * 4096 + ar * 32 + kg * 8];
            al[i] = *(const bf16x8*)&lds[1 * 4096 + ar * 32 + kg * 8];
            const int br = wc * 64 + i * 16 + fr;
            bh[i] = *(const bf16x8*)&lds[2 * 4096 + br * 32 + kg * 8];
            bl[i] = *(const bf16x8*)&lds[3 * 4096 + br * 32 + kg * 8];
        }
#pragma unroll
        for (int i = 0; i < 4; ++i)
#pragma unroll
            for (int j = 0; j < 4; ++j) {
                acc[i][j] = __builtin_amdgcn_mfma_f32_16x16x32_bf16(ah[i], bh[j], acc[i][j], 0, 0, 0);
                acc[i][j] = __builtin_amdgcn_mfma_f32_16x16x32_bf16(al[i], bh[j], acc[i][j], 0, 0, 0);
                acc[i][j] = __builtin_amdgcn_mfma_f32_16x16x32_bf16(ah[i], bl[j], acc[i][j], 0, 0, 0);
            }
        __syncthreads();
    }
    // C/D layout: col=lane&15, row=(lane>>4)*4+reg (m89/m91)
#pragma unroll
    for (int i = 0; i < 4; ++i) {
        const int rbase = m0 + wr * 64 + i * 16 + (lane >> 4) * 4;
#pragma unroll
        for (int r = 0; r < 4; ++r) {
            const int row = rbase + r;
            if (row < M) {
                const float s = scale[row];
#pragma unroll
                for (int j = 0; j < 4; ++j) {
                    const int col = n0 + wc * 64 + j * 16 + fr;
                    C[(size_t)row * Nc + col] = f2b(acc[i][j][r] * s);
                }
            }
        }
    }
}

// ---------------- aggregation: row-sum gather over pre-scaled bf16 rows -----
// out[i][f] = relu( dinv[i] * ( hs[i][f] + sum_e hs[colv[e]][f] ) + bias[f] )
// 2 bf16/lane, gridDim.y feature-halves, 8-deep gather unroll.
// SPLIT: write hi/lo bf16 planes (feeds next GEMM); else fp32.
template <bool SPLIT>
__global__ __launch_bounds__(256) void k_agg(const unsigned short* __restrict__ hs,
                                             const int* __restrict__ rowptr,
                                             const int* __restrict__ colv,
                                             const float* __restrict__ dinv,
                                             const float* __restrict__ bias,
                                             float* __restrict__ outf,
                                             unsigned short* __restrict__ outh,
                                             unsigned short* __restrict__ outl,
                                             int n, int rowlen) {
    const int wid = blockIdx.x * 4 + (threadIdx.x >> 6);
    if (wid >= n) return;
    const int lane = threadIdx.x & 63;
    const int f = blockIdx.y * 128 + lane * 2;
    const unsigned short* base = hs + f;

    float a0, a1;
    {
        ushort2 v = *(const ushort2*)(base + (size_t)wid * rowlen);
        a0 = b2f(v.x); a1 = b2f(v.y);
    }
    const int p0 = rowptr[wid], p1 = rowptr[wid + 1];
    int p = p0;
    for (; p + 8 <= p1; p += 8) {
        int s[8];
#pragma unroll
        for (int j = 0; j < 8; ++j) s[j] = colv[p + j];
        ushort2 v[8];
#pragma unroll
        for (int j = 0; j < 8; ++j) v[j] = *(const ushort2*)(base + (size_t)s[j] * rowlen);
        float x0 = 0.f, x1 = 0.f;
#pragma unroll
        for (int j = 0; j < 8; ++j) { x0 += b2f(v[j].x); x1 += b2f(v[j].y); }
        a0 += x0; a1 += x1;
    }
    for (; p < p1; ++p) {
        ushort2 v = *(const ushort2*)(base + (size_t)colv[p] * rowlen);
        a0 += b2f(v.x); a1 += b2f(v.y);
    }
    const float di = dinv[wid];
    float r0 = di * a0 + bias[f];
    float r1 = di * a1 + bias[f + 1];
    r0 = r0 > 0.f ? r0 : 0.f;
    r1 = r1 > 0.f ? r1 : 0.f;
    if constexpr (SPLIT) {
        unsigned short h0, l0, h1, l1;
        split2(r0, h0, l0); split2(r1, h1, l1);
        size_t o = (size_t)wid * rowlen + f;
        *(ushort2*)(outh + o) = ushort2{h0, h1};
        *(ushort2*)(outl + o) = ushort2{l0, l1};
    } else {
        float* o = outf + (size_t)wid * rowlen + f;
        o[0] = r0; o[1] = r1;
    }
}

extern "C" void kernel_launch(void* const* d_in, const int* in_sizes, int n_in,
                              void* d_out, int out_size, void* d_ws, size_t ws_size,
                              hipStream_t stream) {
    const float* x  = (const float*)d_in[0];
    const int*   ei = (const int*)d_in[1];
    const float* W1 = (const float*)d_in[2];
    const float* b1 = (const float*)d_in[3];
    const float* W2 = (const float*)d_in[4];
    const float* b2 = (const float*)d_in[5];

    const int HID = in_sizes[3];            // 256
    const int IN  = in_sizes[2] / HID;      // 256
    const int OUT = in_sizes[5];            // 128
    const int N   = in_sizes[0] / IN;       // 50000
    const int E   = in_sizes[1] / 2;        // 800000

    const int* src = ei;
    const int* dst = ei + E;

    char* wsb = (char*)d_ws;
    size_t off = 0;
    auto carve = [&](size_t bytes) -> char* {
        char* p = wsb + off;
        off += (bytes + 255) & ~(size_t)255;
        return p;
    };
    unsigned short* xh  = (unsigned short*)carve((size_t)N * IN * 2);   // also h1h
    unsigned short* xl  = (unsigned short*)carve((size_t)N * IN * 2);   // also h1l
    unsigned short* hsb = (unsigned short*)carve((size_t)N * HID * 2);
    unsigned short* gsb = (unsigned short*)carve((size_t)N * OUT * 2);
    float* dinv   = (float*)carve((size_t)N * 4);
    int*   rowptr = (int*)carve((size_t)(N + 1) * 4);
    int*   cnt    = (int*)carve((size_t)N * 4);
    int*   part   = (int*)carve(1024);
    int*   colv   = (int*)carve((size_t)E * 4);
    unsigned short* W1Th = (unsigned short*)carve((size_t)IN * HID * 2);
    unsigned short* W1Tl = (unsigned short*)carve((size_t)IN * HID * 2);
    unsigned short* W2Th = (unsigned short*)carve((size_t)HID * OUT * 2);
    unsigned short* W2Tl = (unsigned short*)carve((size_t)HID * OUT * 2);
    unsigned short* h1h = xh;  // reuse: x planes dead after gemm1
    unsigned short* h1l = xl;
    (void)ws_size; (void)n_in; (void)out_size;

    const int nbN = (N + 255) / 256;   // 196 (<=256 required by k_scan_partial)
    const int nbE = (E + 255) / 256;

    // CSR + dinv
    k_fill_i32<<<nbN, 256, 0, stream>>>(cnt, 0, N);
    k_count<<<nbE, 256, 0, stream>>>(dst, cnt, E);
    k_scan_block<<<nbN, 256, 0, stream>>>(cnt, rowptr, part, dinv, N);
    k_scan_partial<<<1, 256, 0, stream>>>(part, nbN);
    k_scan_add<<<nbN, 256, 0, stream>>>(rowptr, part, N, E);
    k_fill_i32<<<nbN, 256, 0, stream>>>(cnt, 0, N);
    k_fill_col<<<nbE, 256, 0, stream>>>(src, dst, rowptr, cnt, colv, E);

    // operand prep
    k_split<<<2048, 256, 0, stream>>>(x, xh, xl, (N * IN) / 4);
    k_tsplit<<<dim3(HID / 64, IN / 64), 256, 0, stream>>>(W1, W1Th, W1Tl, IN, HID);
    k_tsplit<<<dim3(OUT / 64, HID / 64), 256, 0, stream>>>(W2, W2Th, W2Tl, HID, OUT);

    // layer 1
    k_gemm_split<<<dim3((N + 127) / 128, HID / 128), 256, 0, stream>>>(
        xh, xl, W1Th, W1Tl, dinv, hsb, N, IN, HID);
    k_agg<true><<<dim3((N + 3) / 4, HID / 128), 256, 0, stream>>>(
        hsb, rowptr, colv, dinv, b1, nullptr, h1h, h1l, N, HID);
    // layer 2
    k_gemm_split<<<dim3((N + 127) / 128, OUT / 128), 256, 0, stream>>>(
        h1h, h1l, W2Th, W2Tl, dinv, gsb, N, HID, OUT);
    k_agg<false><<<dim3((N + 3) / 4, OUT / 128), 256, 0, stream>>>(
        gsb, rowptr, colv, dinv, b2, (float*)d_out, nullptr, nullptr, N, OUT);
}

// Round 4
// 276.489 us; speedup vs baseline: 1.0533x; 1.0533x over previous
//
#include <hip/hip_runtime.h>
#include <hip/hip_bf16.h>
#include <cstdint>
#include <cstddef>

// GCN 2-layer forward, MI355X (gfx950).
//   CSR build -> rowptr/colv + dinv
//   x -> (xh,xl) bf16 Dekker-split planes; W1,W2 -> transposed split planes
//   hs = bf16( dinv[m] * (x @ W1) )   3-term split-bf16 MFMA GEMM,
//                                     global_load_lds staging + XOR k-slot swizzle
//   h1 planes = split( relu(dinv*rowsum(hs) + b1) )  (agg emits split planes)
//   gs = bf16( dinv[m] * (h1 @ W2) )
//   out = relu( dinv*rowsum(gs) + b2 )  fp32

typedef short bf16x8 __attribute__((ext_vector_type(8)));
typedef float f32x4 __attribute__((ext_vector_type(4)));
typedef unsigned short u16;
typedef unsigned short u16x8 __attribute__((ext_vector_type(8)));

__device__ __forceinline__ float b2f(u16 u) {
    union { unsigned int i; float f; } c; c.i = ((unsigned int)u) << 16; return c.f;
}
__device__ __forceinline__ u16 f2b(float f) {
    union { float f; unsigned int i; } c; c.f = f;
    return (u16)((c.i + 0x7FFFu + ((c.i >> 16) & 1u)) >> 16);
}
// Dekker-style split: f ~= b2f(hi) + b2f(lo); hi = truncation (exact residual).
__device__ __forceinline__ void split2(float f, u16& hi, u16& lo) {
    union { float f; unsigned int i; } c; c.f = f;
    hi = (u16)(c.i >> 16);
    union { unsigned int i; float f; } h; h.i = c.i & 0xFFFF0000u;
    lo = f2b(f - h.f);
}

// ---------------- CSR build ----------------
__global__ __launch_bounds__(256) void k_fill_i32(int* __restrict__ p, int v, int n) {
    int i = blockIdx.x * 256 + threadIdx.x;
    if (i < n) p[i] = v;
}

__global__ __launch_bounds__(256) void k_count(const int* __restrict__ dst,
                                               int* __restrict__ cnt, int E) {
    int e = blockIdx.x * 256 + threadIdx.x;
    if (e < E) atomicAdd(&cnt[dst[e]], 1);
}

__global__ __launch_bounds__(256) void k_scan_block(const int* __restrict__ cnt,
                                                    int* __restrict__ rowptr,
                                                    int* __restrict__ partial,
                                                    float* __restrict__ dinv, int n) {
    __shared__ int s[256];
    int i = blockIdx.x * 256 + threadIdx.x;
    int v = (i < n) ? cnt[i] : 0;
    if (i < n) dinv[i] = rsqrtf((float)(v + 1));
    s[threadIdx.x] = v;
    __syncthreads();
    for (int off = 1; off < 256; off <<= 1) {
        int t = (threadIdx.x >= off) ? s[threadIdx.x - off] : 0;
        __syncthreads();
        s[threadIdx.x] += t;
        __syncthreads();
    }
    if (i < n) rowptr[i] = s[threadIdx.x] - v;
    if (threadIdx.x == 255) partial[blockIdx.x] = s[255];
}

__global__ __launch_bounds__(256) void k_scan_partial(int* __restrict__ partial, int nb) {
    __shared__ int s[256];
    int v = (threadIdx.x < nb) ? partial[threadIdx.x] : 0;
    s[threadIdx.x] = v;
    __syncthreads();
    for (int off = 1; off < 256; off <<= 1) {
        int t = (threadIdx.x >= off) ? s[threadIdx.x - off] : 0;
        __syncthreads();
        s[threadIdx.x] += t;
        __syncthreads();
    }
    if (threadIdx.x < nb) partial[threadIdx.x] = s[threadIdx.x] - v;
}

// also zeroes cnt (cursor reuse) — cnt is dead after k_scan_block
__global__ __launch_bounds__(256) void k_scan_add(int* __restrict__ rowptr,
                                                  const int* __restrict__ partial,
                                                  int* __restrict__ cnt,
                                                  int n, int e) {
    int i = blockIdx.x * 256 + threadIdx.x;
    if (i < n) { rowptr[i] += partial[blockIdx.x]; cnt[i] = 0; }
    if (i == 0) rowptr[n] = e;
}

__global__ __launch_bounds__(256) void k_fill_col(const int* __restrict__ src,
                                                  const int* __restrict__ dst,
                                                  const int* __restrict__ rowptr,
                                                  int* __restrict__ cur,
                                                  int* __restrict__ colv, int E) {
    int e = blockIdx.x * 256 + threadIdx.x;
    if (e < E) {
        int d = dst[e];
        int p = rowptr[d] + atomicAdd(&cur[d], 1);
        colv[p] = src[e];
    }
}

// ---------------- fp32 -> split bf16 planes (elementwise, float4) ----------
__global__ __launch_bounds__(256) void k_split(const float* __restrict__ in,
                                               u16* __restrict__ hi,
                                               u16* __restrict__ lo, int n4) {
    int i = blockIdx.x * 256 + threadIdx.x;
    const int stride = gridDim.x * 256;
    for (; i < n4; i += stride) {
        float4 v = ((const float4*)in)[i];
        ushort4 h, l;
        split2(v.x, h.x, l.x); split2(v.y, h.y, l.y);
        split2(v.z, h.z, l.z); split2(v.w, h.w, l.w);
        ((ushort4*)hi)[i] = h;
        ((ushort4*)lo)[i] = l;
    }
}

// ---------------- transpose + split: src[R][C] -> dh/dl[C][R] --------------
__global__ __launch_bounds__(256) void k_tsplit(const float* __restrict__ src,
                                                u16* __restrict__ dh,
                                                u16* __restrict__ dl,
                                                int R, int C) {
    __shared__ float tile[64][65];
    int r0 = blockIdx.y * 64, c0 = blockIdx.x * 64;
    for (int i = threadIdx.x; i < 4096; i += 256) {
        int r = i >> 6, c = i & 63;
        tile[r][c] = src[(size_t)(r0 + r) * C + c0 + c];
    }
    __syncthreads();
    for (int i = threadIdx.x; i < 4096; i += 256) {
        int r = i >> 6, c = i & 63;
        float v = tile[c][r];
        u16 h, l;
        split2(v, h, l);
        size_t o = (size_t)(c0 + r) * R + r0 + c;
        dh[o] = h;
        dl[o] = l;
    }
}

// ---------------- pure-bf16 split GEMM (m97 structure + k-slot XOR swizzle) --
// C[m][n] = bf16( scale[m] * sum_k (ah+al)[m][k]*(bh+bl)[n][k] ), 3-term.
// Tile 128x128, BK=32, 4 waves. LDS: 4 linear planes [128][32] bf16 = 32 KB,
// staged via global_load_lds width=16. Swizzle (G21: both-sides-or-neither):
// LDS slot (row, k16) holds global k-chunk (k16 ^ ((row>>1)&3)); staging
// pre-swizzles the GLOBAL source address, ds_read applies the same XOR.
// Spreads each 8-lane b128 issue group across all 8 bank-quads (was 2).
__global__ __launch_bounds__(256) void k_gemm_split(const u16* __restrict__ Ah,
                                                    const u16* __restrict__ Al,
                                                    const u16* __restrict__ Bh,
                                                    const u16* __restrict__ Bl,
                                                    const float* __restrict__ scale,
                                                    u16* __restrict__ C,
                                                    int M, int K, int Nc) {
    __shared__ __align__(16) u16 lds[4 * 128 * 32];  // planes: Ah Al Bh Bl
    const int tid = threadIdx.x;
    const int m0 = blockIdx.x * 128, n0 = blockIdx.y * 128;
    const int w = tid >> 6, lane = tid & 63;
    const int wr = w >> 1, wc = w & 1;
    const int fr = lane & 15, kg = lane >> 4;

    f32x4 acc[4][4] = {};

    for (int k0 = 0; k0 < K; k0 += 32) {
#pragma unroll
        for (int c = 0; c < 8; ++c) {
            const int r = c * 4 + w;            // chunk id 0..31, wave-uniform
            const int plane = r >> 3;           // wave-uniform
            const int wch = (r & 7) * 64 + lane;
            const int row = wch >> 2;           // 0..127
            const int k16 = wch & 3;            // 16B slot in row
            const int kc = (k16 ^ ((row >> 1) & 3)) * 8;  // swizzled global k (shorts)
            const u16* gp;
            if (plane == 0) {
                int rg = m0 + row; rg = rg < M ? rg : M - 1;
                gp = Ah + (size_t)rg * K + k0 + kc;
            } else if (plane == 1) {
                int rg = m0 + row; rg = rg < M ? rg : M - 1;
                gp = Al + (size_t)rg * K + k0 + kc;
            } else if (plane == 2) {
                gp = Bh + (size_t)(n0 + row) * K + k0 + kc;
            } else {
                gp = Bl + (size_t)(n0 + row) * K + k0 + kc;
            }
            __builtin_amdgcn_global_load_lds(
                (const __attribute__((address_space(1))) void*)gp,
                (__attribute__((address_space(3))) void*)(lds + (size_t)r * 512),
                16, 0, 0);
        }
        __syncthreads();
        bf16x8 ah[4], al[4], bh[4], bl[4];
#pragma unroll
        for (int i = 0; i < 4; ++i) {
            const int ar = wr * 64 + i * 16 + fr;
            const int sa = (kg ^ ((ar >> 1) & 3)) * 8;
            ah[i] = *(const bf16x8*)&lds[0 * 4096 + ar * 32 + sa];
            al[i] = *(const bf16x8*)&lds[1 * 4096 + ar * 32 + sa];
            const int br = wc * 64 + i * 16 + fr;
            const int sb = (kg ^ ((br >> 1) & 3)) * 8;
            bh[i] = *(const bf16x8*)&lds[2 * 4096 + br * 32 + sb];
            bl[i] = *(const bf16x8*)&lds[3 * 4096 + br * 32 + sb];
        }
#pragma unroll
        for (int i = 0; i < 4; ++i)
#pragma unroll
            for (int j = 0; j < 4; ++j) {
                acc[i][j] = __builtin_amdgcn_mfma_f32_16x16x32_bf16(ah[i], bh[j], acc[i][j], 0, 0, 0);
                acc[i][j] = __builtin_amdgcn_mfma_f32_16x16x32_bf16(al[i], bh[j], acc[i][j], 0, 0, 0);
                acc[i][j] = __builtin_amdgcn_mfma_f32_16x16x32_bf16(ah[i], bl[j], acc[i][j], 0, 0, 0);
            }
        __syncthreads();
    }
    // C/D layout: col=lane&15, row=(lane>>4)*4+reg (m89/m91)
#pragma unroll
    for (int i = 0; i < 4; ++i) {
        const int rbase = m0 + wr * 64 + i * 16 + (lane >> 4) * 4;
#pragma unroll
        for (int r = 0; r < 4; ++r) {
            const int row = rbase + r;
            if (row < M) {
                const float s = scale[row];
#pragma unroll
                for (int j = 0; j < 4; ++j) {
                    const int col = n0 + wc * 64 + j * 16 + fr;
                    C[(size_t)row * Nc + col] = f2b(acc[i][j][r] * s);
                }
            }
        }
    }
}

// ---------------- aggregation: row-sum gather over pre-scaled bf16 rows -----
// out[i][f] = relu( dinv[i] * ( hs[i][f] + sum_e hs[colv[e]][f] ) + bias[f] )
// EPI edges per iteration; each LPR=64/EPI lane group reads one full row as
// contiguous bf16x8 (16B/lane). Butterfly shfl_xor combines groups at end.
// U-deep unroll -> U*EPI rows in flight. SPLIT: emit hi/lo bf16 planes.
template <int F, int EPI, int U, bool SPLIT>
__global__ __launch_bounds__(256) void k_agg(const u16* __restrict__ hs,
                                             const int* __restrict__ rowptr,
                                             const int* __restrict__ colv,
                                             const float* __restrict__ dinv,
                                             const float* __restrict__ bias,
                                             float* __restrict__ outf,
                                             u16* __restrict__ outh,
                                             u16* __restrict__ outl, int n) {
    constexpr int LPR = 64 / EPI;  // lanes per row; F == LPR*8
    const int wid = blockIdx.x * 4 + (threadIdx.x >> 6);
    if (wid >= n) return;
    const int lane = threadIdx.x & 63;
    const int sub = lane / LPR;
    const int fb = (lane % LPR) * 8;
    const u16* base = hs + fb;

    float acc[8] = {};
    const int p0 = rowptr[wid], p1 = rowptr[wid + 1];
    const int nblk = (p1 - p0) / (U * EPI);
    const int* cp = colv + p0 + sub;
    for (int b = 0; b < nblk; ++b) {
        int s[U];
#pragma unroll
        for (int u = 0; u < U; ++u) s[u] = cp[u * EPI];
        u16x8 v[U];
#pragma unroll
        for (int u = 0; u < U; ++u) v[u] = *(const u16x8*)(base + (size_t)s[u] * F);
#pragma unroll
        for (int u = 0; u < U; ++u)
#pragma unroll
            for (int j = 0; j < 8; ++j) acc[j] += b2f(v[u][j]);
        cp += U * EPI;
    }
    for (int p = p0 + nblk * U * EPI + sub; p < p1; p += EPI) {
        u16x8 v = *(const u16x8*)(base + (size_t)colv[p] * F);
#pragma unroll
        for (int j = 0; j < 8; ++j) acc[j] += b2f(v[j]);
    }
#pragma unroll
    for (int m = LPR; m < 64; m <<= 1)
#pragma unroll
        for (int j = 0; j < 8; ++j) acc[j] += __shfl_xor(acc[j], m, 64);

    if (sub == 0) {
        u16x8 sv = *(const u16x8*)(base + (size_t)wid * F);
        const float di = dinv[wid];
        float r[8];
#pragma unroll
        for (int j = 0; j < 8; ++j) {
            float t = di * (acc[j] + b2f(sv[j])) + bias[fb + j];
            r[j] = t > 0.f ? t : 0.f;
        }
        const size_t o = (size_t)wid * F + fb;
        if constexpr (SPLIT) {
            u16x8 hv, lv;
#pragma unroll
            for (int j = 0; j < 8; ++j) { u16 h, l; split2(r[j], h, l); hv[j] = h; lv[j] = l; }
            *(u16x8*)(outh + o) = hv;
            *(u16x8*)(outl + o) = lv;
        } else {
            float* op = outf + o;
            *(float4*)(op)     = make_float4(r[0], r[1], r[2], r[3]);
            *(float4*)(op + 4) = make_float4(r[4], r[5], r[6], r[7]);
        }
    }
}

extern "C" void kernel_launch(void* const* d_in, const int* in_sizes, int n_in,
                              void* d_out, int out_size, void* d_ws, size_t ws_size,
                              hipStream_t stream) {
    const float* x  = (const float*)d_in[0];
    const int*   ei = (const int*)d_in[1];
    const float* W1 = (const float*)d_in[2];
    const float* b1 = (const float*)d_in[3];
    const float* W2 = (const float*)d_in[4];
    const float* b2 = (const float*)d_in[5];

    const int HID = in_sizes[3];            // 256
    const int IN  = in_sizes[2] / HID;      // 256
    const int OUT = in_sizes[5];            // 128
    const int N   = in_sizes[0] / IN;       // 50000
    const int E   = in_sizes[1] / 2;        // 800000

    const int* src = ei;
    const int* dst = ei + E;

    char* wsb = (char*)d_ws;
    size_t off = 0;
    auto carve = [&](size_t bytes) -> char* {
        char* p = wsb + off;
        off += (bytes + 255) & ~(size_t)255;
        return p;
    };
    u16* xh  = (u16*)carve((size_t)N * IN * 2);   // also h1h
    u16* xl  = (u16*)carve((size_t)N * IN * 2);   // also h1l
    u16* hsb = (u16*)carve((size_t)N * HID * 2);
    u16* gsb = (u16*)carve((size_t)N * OUT * 2);
    float* dinv   = (float*)carve((size_t)N * 4);
    int*   rowptr = (int*)carve((size_t)(N + 1) * 4);
    int*   cnt    = (int*)carve((size_t)N * 4);
    int*   part   = (int*)carve(1024);
    int*   colv   = (int*)carve((size_t)E * 4);
    u16* W1Th = (u16*)carve((size_t)IN * HID * 2);
    u16* W1Tl = (u16*)carve((size_t)IN * HID * 2);
    u16* W2Th = (u16*)carve((size_t)HID * OUT * 2);
    u16* W2Tl = (u16*)carve((size_t)HID * OUT * 2);
    u16* h1h = xh;  // reuse: x planes dead after gemm1
    u16* h1l = xl;
    (void)ws_size; (void)n_in; (void)out_size;

    const int nbN = (N + 255) / 256;   // 196 (<=256 required by k_scan_partial)
    const int nbE = (E + 255) / 256;

    // CSR + dinv
    k_fill_i32<<<nbN, 256, 0, stream>>>(cnt, 0, N);
    k_count<<<nbE, 256, 0, stream>>>(dst, cnt, E);
    k_scan_block<<<nbN, 256, 0, stream>>>(cnt, rowptr, part, dinv, N);
    k_scan_partial<<<1, 256, 0, stream>>>(part, nbN);
    k_scan_add<<<nbN, 256, 0, stream>>>(rowptr, part, cnt, N, E);
    k_fill_col<<<nbE, 256, 0, stream>>>(src, dst, rowptr, cnt, colv, E);

    // operand prep
    k_split<<<2048, 256, 0, stream>>>(x, xh, xl, (N * IN) / 4);
    k_tsplit<<<dim3(HID / 64, IN / 64), 256, 0, stream>>>(W1, W1Th, W1Tl, IN, HID);
    k_tsplit<<<dim3(OUT / 64, HID / 64), 256, 0, stream>>>(W2, W2Th, W2Tl, HID, OUT);

    // layer 1
    k_gemm_split<<<dim3((N + 127) / 128, HID / 128), 256, 0, stream>>>(
        xh, xl, W1Th, W1Tl, dinv, hsb, N, IN, HID);
    k_agg<256, 2, 4, true><<<(N + 3) / 4, 256, 0, stream>>>(
        hsb, rowptr, colv, dinv, b1, nullptr, h1h, h1l, N);
    // layer 2
    k_gemm_split<<<dim3((N + 127) / 128, OUT / 128), 256, 0, stream>>>(
        h1h, h1l, W2Th, W2Tl, dinv, gsb, N, HID, OUT);
    k_agg<128, 4, 2, false><<<(N + 3) / 4, 256, 0, stream>>>(
        gsb, rowptr, colv, dinv, b2, (float*)d_out, nullptr, nullptr, N);
}